// Round 1
// baseline (81.621 us; speedup 1.0000x reference)
//
#include <hip/hip_runtime.h>

#define B_TOTAL 131072
#define NF 32
#define NA 8
#define NH 64

using frag_ab = __attribute__((ext_vector_type(8))) short;   // 8 bf16 (4 VGPRs)
using frag_cd = __attribute__((ext_vector_type(4))) float;   // 4 fp32

__device__ __forceinline__ unsigned short f2bf(float x) {
  unsigned u = __float_as_uint(x);
  u = (u + 0x7FFFu + ((u >> 16) & 1u)) >> 16;   // RNE
  return (unsigned short)u;
}

// fa[b][c]: c<32 -> f_t, 32..39 -> a_t, 40 -> 1.0 (bias row), else 0
__global__ void build_fa_kernel(const float* __restrict__ ft, const float* __restrict__ at,
                                unsigned short* __restrict__ fa) {
  int idx = blockIdx.x * 256 + threadIdx.x;   // B*64 total
  int b = idx >> 6, c = idx & 63;
  float v;
  if (c < NF)            v = ft[b * NF + c];
  else if (c < NF + NA)  v = at[b * NA + (c - NF)];
  else if (c == 40)      v = 1.0f;
  else                   v = 0.0f;
  fa[idx] = f2bf(v);
}

// W1 packed to per-lane B-fragment order; row i==40 carries b1 (bias fold)
// idx = (((f*2+ks)*4+nt)*64+lane)*8+j ; value = W1[f][i=ks*32+(l>>4)*8+j][h=nt*16+(l&15)]
__global__ void pack_w1_kernel(const float* __restrict__ W1, const float* __restrict__ b1,
                               unsigned short* __restrict__ w1p) {
  int idx = blockIdx.x * 256 + threadIdx.x;   // 131072 total
  int j = idx & 7, l = (idx >> 3) & 63, nt = (idx >> 9) & 3, ks = (idx >> 11) & 1, f = idx >> 12;
  int g = l >> 4, c = l & 15;
  int i = ks * 32 + g * 8 + j;
  int h = nt * 16 + c;
  float v = 0.0f;
  if (i < NF + NA)            v = W1[(f * (NF + NA) + i) * NH + h];
  else if (i == NF + NA)      v = b1[f * NH + h];
  w1p[idx] = f2bf(v);
}

template <int CTRL>
__device__ __forceinline__ float dpp_xor_add(float v) {   // VALU-pipe butterfly step
  int m = __builtin_amdgcn_update_dpp(0, __float_as_int(v), CTRL, 0xF, 0xF, true);
  return v + __int_as_float(m);
}
template <int PAT>
__device__ __forceinline__ float swz_xor_add(float v) {   // ds_swizzle butterfly step
  int m = __builtin_amdgcn_ds_swizzle(__float_as_int(v), PAT);
  return v + __int_as_float(m);
}

__global__ __launch_bounds__(256, 2) void fused_mlp_kernel(
    const unsigned short* __restrict__ fa, const unsigned short* __restrict__ w1p,
    const float* __restrict__ w2, const float* __restrict__ b2,
    const float* __restrict__ ft, float* __restrict__ out) {
  __shared__ __align__(16) unsigned short wlds[2][4096];  // 2 x 8 KB weight dbuf
  __shared__ __align__(16) float w2l[NF * NH];            // 8 KB
  __shared__ __align__(16) float outl[256][36];           // 36 KB (36: b128-aligned, 2-way banks)

  const int t = threadIdx.x;
  const int wv = t >> 6;
  const int l = t & 63;
  const int g = l >> 4;
  const int c = l & 15;
  const long row0 = (long)blockIdx.x * 256;
  const int wrow = wv * 64;   // wave owns 64 rows

  // W2 -> LDS (once)
  {
    const float4* s = (const float4*)w2;
    float4* d = (float4*)w2l;
    d[t] = s[t];
    d[t + 256] = s[t + 256];
  }

  // A fragments: held in registers across all 32 f iterations
  frag_ab afr[4][2];
#pragma unroll
  for (int rt = 0; rt < 4; ++rt)
#pragma unroll
    for (int ks = 0; ks < 2; ++ks)
      afr[rt][ks] = *(const frag_ab*)(fa + (row0 + wrow + rt * 16 + c) * 64 + ks * 32 + g * 8);

  // stage f=0 weights (linear LDS dest = wave-uniform base + lane*16)
  {
    const unsigned short* src = w1p + t * 8;
    __builtin_amdgcn_global_load_lds((const __attribute__((address_space(1))) void*)(src),
                                     (__attribute__((address_space(3))) void*)(&wlds[0][t * 8]), 16, 0, 0);
    __builtin_amdgcn_global_load_lds((const __attribute__((address_space(1))) void*)(src + 2048),
                                     (__attribute__((address_space(3))) void*)(&wlds[0][t * 8 + 2048]), 16, 0, 0);
  }
  __syncthreads();

  const frag_cd zero4 = {0.f, 0.f, 0.f, 0.f};

  for (int f = 0; f < NF; ++f) {
    const int buf = f & 1;
    if (f < NF - 1) {   // prefetch next f's weights into other buffer
      const unsigned short* src = w1p + (f + 1) * 4096 + t * 8;
      __builtin_amdgcn_global_load_lds((const __attribute__((address_space(1))) void*)(src),
                                       (__attribute__((address_space(3))) void*)(&wlds[buf ^ 1][t * 8]), 16, 0, 0);
      __builtin_amdgcn_global_load_lds((const __attribute__((address_space(1))) void*)(src + 2048),
                                       (__attribute__((address_space(3))) void*)(&wlds[buf ^ 1][t * 8 + 2048]), 16, 0, 0);
    }

    // B fragments for this f
    frag_ab bfr[2][4];
#pragma unroll
    for (int ks = 0; ks < 2; ++ks)
#pragma unroll
      for (int nt = 0; nt < 4; ++nt)
        bfr[ks][nt] = *(const frag_ab*)&wlds[buf][((ks * 4 + nt) * 64 + l) * 8];

    // layer 1: h_pre = fa @ W1[f]  (bias folded via K-row 40)
    frag_cd acc[4][4];
#pragma unroll
    for (int rt = 0; rt < 4; ++rt)
#pragma unroll
      for (int nt = 0; nt < 4; ++nt) {
        acc[rt][nt] = __builtin_amdgcn_mfma_f32_16x16x32_bf16(afr[rt][0], bfr[0][nt], zero4, 0, 0, 0);
        acc[rt][nt] = __builtin_amdgcn_mfma_f32_16x16x32_bf16(afr[rt][1], bfr[1][nt], acc[rt][nt], 0, 0, 0);
      }

    float w2v[4];
#pragma unroll
    for (int nt = 0; nt < 4; ++nt) w2v[nt] = w2l[f * NH + nt * 16 + c];

    // layer 2: relu + dot(W2) + 16-lane reduce (xor1/2 on VALU via DPP, xor4/8 via ds_swizzle)
#pragma unroll
    for (int rt = 0; rt < 4; ++rt) {
      float p[4];
#pragma unroll
      for (int j = 0; j < 4; ++j) {
        float s = fmaxf(acc[rt][0][j], 0.f) * w2v[0];
        s += fmaxf(acc[rt][1][j], 0.f) * w2v[1];
        s += fmaxf(acc[rt][2][j], 0.f) * w2v[2];
        s += fmaxf(acc[rt][3][j], 0.f) * w2v[3];
        s = dpp_xor_add<0xB1>(s);   // quad_perm [1,0,3,2] = lane^1
        s = dpp_xor_add<0x4E>(s);   // quad_perm [2,3,0,1] = lane^2
        p[j] = s;
      }
      float s01 = (l & 1) ? p[1] : p[0];
      float s23 = (l & 1) ? p[3] : p[2];
      float s = (l & 2) ? s23 : s01;         // lane owns value j = l&3
      s = swz_xor_add<0x101F>(s);            // lane^4
      s = swz_xor_add<0x201F>(s);            // lane^8 -> full 16-lane sum
      if (((l >> 2) & 3) == rt) {            // one distinct row per lane across the 4 rt
        int row = wrow + rt * 16 + g * 4 + (l & 3);
        outl[row][f] = s;
      }
    }
    __syncthreads();   // protects both wlds dbuf rotation and outl visibility
  }

  // epilogue: out = outl + b2 + f_t (skip connection), coalesced float4
  const float4* ftv = (const float4*)(ft + row0 * NF);
  float4* outv = (float4*)(out + row0 * NF);
  const float4* b2v = (const float4*)b2;
#pragma unroll
  for (int k = 0; k < 8; ++k) {
    int flat = k * 256 + t;   // 2048 float4 = 256 rows x 32 f
    int f4 = flat & 7;
    int row = flat >> 3;
    float4 v = *(const float4*)&outl[row][f4 * 4];
    float4 bb = b2v[f4];
    float4 x = ftv[flat];
    float4 r;
    r.x = v.x + bb.x + x.x;
    r.y = v.y + bb.y + x.y;
    r.z = v.z + bb.z + x.z;
    r.w = v.w + bb.w + x.w;
    outv[flat] = r;
  }
}

extern "C" void kernel_launch(void* const* d_in, const int* in_sizes, int n_in,
                              void* d_out, int out_size, void* d_ws, size_t ws_size,
                              hipStream_t stream) {
  const float* ft = (const float*)d_in[0];
  const float* at = (const float*)d_in[1];
  const float* W1 = (const float*)d_in[2];
  const float* b1 = (const float*)d_in[3];
  const float* W2 = (const float*)d_in[4];
  const float* b2 = (const float*)d_in[5];
  float* out = (float*)d_out;

  unsigned short* w1p = (unsigned short*)d_ws;                          // 256 KB
  unsigned short* fa  = (unsigned short*)((char*)d_ws + (1u << 20));    // 16 MB @ 1 MB offset

  pack_w1_kernel<<<(NF * 2 * 4 * 64 * 8) / 256, 256, 0, stream>>>(W1, b1, w1p);
  build_fa_kernel<<<(B_TOTAL * 64) / 256, 256, 0, stream>>>(ft, at, fa);
  fused_mlp_kernel<<<B_TOTAL / 256, 256, 0, stream>>>(fa, w1p, W2, b2, ft, out);
}